// Round 2
// baseline (375.147 us; speedup 1.0000x reference)
//
#include <hip/hip_runtime.h>

// Round 2: inputs/outputs are FP32 (per reference). Convert fp32->bf16 during
// LDS staging; MFMA pipeline in bf16 with fp32 accumulation.
//   k1: qkv GEMM  x[32768,256](f32) @ w_qkv^T -> Q,K (bf16 row-major), V^T [B,D,S] bf16
//   k2: flash attention, S^T orientation (K*Q^T), online softmax, shfl-based P^T frags
//   k3: proj GEMM ctx(bf16) @ w_out^T(f32->bf16) + b_out(f32) -> out (f32)
// ws (ushort elems): Q/ctx[0], K[NE], Vt[2NE], NE=16*2048*256 (48 MiB total).
// ctx aliases Q: each attn block reads only its own Q rows (into regs, at start)
// and writes only those same rows (at end) -> no cross-block hazard.

typedef short bf16x8 __attribute__((ext_vector_type(8)));
typedef float f32x4 __attribute__((ext_vector_type(4)));

#define MFMA16(a, b, c) __builtin_amdgcn_mfma_f32_16x16x32_bf16((a), (b), (c), 0, 0, 0)

__device__ __forceinline__ unsigned short f2bf(float f) {
  unsigned int x;
  __builtin_memcpy(&x, &f, 4);
  x = x + 0x7fffu + ((x >> 16) & 1u);  // RNE (finite values only)
  return (unsigned short)(x >> 16);
}
__device__ __forceinline__ unsigned int pack2(float a, float b) {
  return (unsigned int)f2bf(a) | ((unsigned int)f2bf(b) << 16);
}

// ---------------- QKV GEMM ----------------
// grid(6, 256), block 256. Tile 128m x 128n, BK=64. fp32 global -> bf16 LDS.
// LDS XOR-swizzled at 16B-chunk granularity (c' = c ^ (row&7)).
__global__ __launch_bounds__(256, 2) void qkv_kernel(
    const float* __restrict__ X, const float* __restrict__ W,
    unsigned short* __restrict__ Q, unsigned short* __restrict__ Kp,
    unsigned short* __restrict__ Vt) {
  __shared__ unsigned short Al[128 * 64];
  __shared__ unsigned short Bl[128 * 64];
  const int n0 = blockIdx.x * 128;
  const int m0 = blockIdx.y * 128;
  const int t = threadIdx.x;
  const int w = t >> 6, lane = t & 63, lo = lane & 15, quad = lane >> 4;
  const int aw = (w >> 1) * 64, bw = (w & 1) * 64;

  f32x4 zero4 = {0.f, 0.f, 0.f, 0.f};
  f32x4 acc[4][4];
#pragma unroll
  for (int i = 0; i < 4; i++)
#pragma unroll
    for (int j = 0; j < 4; j++) acc[i][j] = zero4;

  for (int kb = 0; kb < 4; ++kb) {
    const int k0 = kb * 64;
#pragma unroll
    for (int rr = 0; rr < 4; ++rr) {  // 1024 8-elem chunks per tile
      int ci = rr * 256 + t;
      int row = ci >> 3, c = ci & 7, cs = c ^ (row & 7);
      const float* xp = X + (size_t)(m0 + row) * 256 + k0 + c * 8;
      float4 a0 = *(const float4*)xp, a1 = *(const float4*)(xp + 4);
      uint4 ua;
      ua.x = pack2(a0.x, a0.y);
      ua.y = pack2(a0.z, a0.w);
      ua.z = pack2(a1.x, a1.y);
      ua.w = pack2(a1.z, a1.w);
      *(uint4*)(&Al[row * 64 + cs * 8]) = ua;
      const float* wp = W + (size_t)(n0 + row) * 256 + k0 + c * 8;
      float4 b0 = *(const float4*)wp, b1 = *(const float4*)(wp + 4);
      uint4 ub;
      ub.x = pack2(b0.x, b0.y);
      ub.y = pack2(b0.z, b0.w);
      ub.z = pack2(b1.x, b1.y);
      ub.w = pack2(b1.z, b1.w);
      *(uint4*)(&Bl[row * 64 + cs * 8]) = ub;
    }
    __syncthreads();
#pragma unroll
    for (int ks = 0; ks < 2; ++ks) {
      const int c = ks * 4 + quad, cs = c ^ (lo & 7);
      bf16x8 af[4], bfr[4];
#pragma unroll
      for (int mt = 0; mt < 4; ++mt)
        af[mt] = *(const bf16x8*)(&Al[(aw + mt * 16 + lo) * 64 + cs * 8]);
#pragma unroll
      for (int nt = 0; nt < 4; ++nt)
        bfr[nt] = *(const bf16x8*)(&Bl[(bw + nt * 16 + lo) * 64 + cs * 8]);
#pragma unroll
      for (int mt = 0; mt < 4; ++mt)
#pragma unroll
        for (int nt = 0; nt < 4; ++nt)
          acc[mt][nt] = MFMA16(af[mt], bfr[nt], acc[mt][nt]);
    }
    __syncthreads();
  }

  // epilogue: C[m][n], m = mb+mt*16+quad*4+reg, n = nb+nt*16+lo. Branch uniform per block.
  const int mb = m0 + aw, nb = n0 + bw;
  if (n0 < 256) {
#pragma unroll
    for (int mt = 0; mt < 4; ++mt)
#pragma unroll
      for (int nt = 0; nt < 4; ++nt) {
        int m = mb + mt * 16 + quad * 4;
        int n = nb + nt * 16 + lo;
        unsigned short* p = Q + (size_t)m * 256 + n;
        p[0] = f2bf(acc[mt][nt][0]);
        p[256] = f2bf(acc[mt][nt][1]);
        p[512] = f2bf(acc[mt][nt][2]);
        p[768] = f2bf(acc[mt][nt][3]);
      }
  } else if (n0 < 512) {
#pragma unroll
    for (int mt = 0; mt < 4; ++mt)
#pragma unroll
      for (int nt = 0; nt < 4; ++nt) {
        int m = mb + mt * 16 + quad * 4;
        int n = nb + nt * 16 + lo - 256;
        unsigned short* p = Kp + (size_t)m * 256 + n;
        p[0] = f2bf(acc[mt][nt][0]);
        p[256] = f2bf(acc[mt][nt][1]);
        p[512] = f2bf(acc[mt][nt][2]);
        p[768] = f2bf(acc[mt][nt][3]);
      }
  } else {
    // V stored transposed: Vt[b][d][s]; regs are 4 consecutive s -> one 8B store
#pragma unroll
    for (int mt = 0; mt < 4; ++mt)
#pragma unroll
      for (int nt = 0; nt < 4; ++nt) {
        int m = mb + mt * 16 + quad * 4;
        int d = nb + nt * 16 + lo - 512;
        int b = m >> 11, s = m & 2047;
        uint2 v;
        v.x = pack2(acc[mt][nt][0], acc[mt][nt][1]);
        v.y = pack2(acc[mt][nt][2], acc[mt][nt][3]);
        *(uint2*)(Vt + ((size_t)(b * 256 + d)) * 2048 + s) = v;
      }
  }
}

// ---------------- Flash attention ----------------
// grid(32, 16), block 256 (4 waves x 16 q-rows). BM=BN=64.
// S^T = K*Q^T: each lane owns one q-row (s_q = lane&15): scalar online-softmax
// state, P^T B-frags built with 16 __shfl's (no LDS round-trip).
__global__ __launch_bounds__(256, 2) void attn_kernel(
    const unsigned short* __restrict__ Q, const unsigned short* __restrict__ K,
    const unsigned short* __restrict__ Vt, unsigned short* __restrict__ C) {
  __shared__ unsigned short Kl[64 * 256];  // [s_k][d], chunk-swizzled c ^= (row&15)
  __shared__ unsigned short Vl[256 * 64];  // V^T tile [d][s_k], chunk-swizzled c ^= (d&7)
  const int qt = blockIdx.x, b = blockIdx.y;
  const int t = threadIdx.x;
  const int w = t >> 6, lane = t & 63, lo = lane & 15, quad = lane >> 4;
  constexpr float SCALE_LOG2E = 0.0625f * 1.4426950408889634f;

  const int qrow = b * 2048 + qt * 64 + w * 16 + lo;
  const unsigned short* qp = Q + (size_t)qrow * 256;
  bf16x8 qf[8];
#pragma unroll
  for (int ks = 0; ks < 8; ++ks)
    qf[ks] = *(const bf16x8*)(qp + ks * 32 + quad * 8);

  f32x4 zero4 = {0.f, 0.f, 0.f, 0.f};
  f32x4 oacc[16];
#pragma unroll
  for (int i = 0; i < 16; i++) oacc[i] = zero4;
  float m_run = -1e30f, l_run = 0.f;

  const unsigned short* Kb = K + (size_t)b * 2048 * 256;
  const unsigned short* Vb = Vt + (size_t)b * 256 * 2048;

  for (int it = 0; it < 32; ++it) {
    const int kv0 = it * 64;
#pragma unroll
    for (int rr = 0; rr < 8; ++rr) {  // stage K (64x256) and V^T (256x64) tiles
      int ci = rr * 256 + t;
      int krow = ci >> 5, kc = ci & 31;
      int kcs = (kc & 16) | ((kc ^ (krow & 15)) & 15);
      *(int4*)(&Kl[krow * 256 + kcs * 8]) =
          *(const int4*)(Kb + (size_t)(kv0 + krow) * 256 + kc * 8);
      int vd = ci >> 3, vc = ci & 7, vcs = vc ^ (vd & 7);
      *(int4*)(&Vl[vd * 64 + vcs * 8]) =
          *(const int4*)(Vb + (size_t)vd * 2048 + kv0 + vc * 8);
    }
    __syncthreads();

    // S^T[s_k][s_q]: A = K rows, B = Q frags
    f32x4 sacc[4];
#pragma unroll
    for (int r = 0; r < 4; r++) sacc[r] = zero4;
#pragma unroll
    for (int ks = 0; ks < 8; ++ks) {
      const int c = ks * 4 + quad;
      const int cs = (c & 16) | ((c ^ lo) & 15);
#pragma unroll
      for (int r = 0; r < 4; ++r) {
        bf16x8 kf = *(const bf16x8*)(&Kl[(r * 16 + lo) * 256 + cs * 8]);
        sacc[r] = MFMA16(kf, qf[ks], sacc[r]);
      }
    }

    // online softmax; each lane: 16 s_k values for its s_q; cross-quad reduce
    float p[4][4];
    float cmax = -1e30f;
#pragma unroll
    for (int r = 0; r < 4; r++)
#pragma unroll
      for (int i = 0; i < 4; i++) {
        p[r][i] = sacc[r][i] * SCALE_LOG2E;
        cmax = fmaxf(cmax, p[r][i]);
      }
    cmax = fmaxf(cmax, __shfl_xor(cmax, 16));
    cmax = fmaxf(cmax, __shfl_xor(cmax, 32));
    float mnew = fmaxf(m_run, cmax);
    float rsum = 0.f;
#pragma unroll
    for (int r = 0; r < 4; r++)
#pragma unroll
      for (int i = 0; i < 4; i++) {
        p[r][i] = exp2f(p[r][i] - mnew);
        rsum += p[r][i];
      }
    rsum += __shfl_xor(rsum, 16);
    rsum += __shfl_xor(rsum, 32);
    float alpha = exp2f(m_run - mnew);
    m_run = mnew;
    l_run = l_run * alpha + rsum;
#pragma unroll
    for (int i = 0; i < 16; i++) oacc[i] *= alpha;

    // P^T B-operand frags via shfl: dword dd from src lane lo+16*(2(quad&1)+(dd>>1)),
    // register pk[2*ks2 + (quad>>1)][dd&1]
    unsigned int pk[4][2];
#pragma unroll
    for (int r = 0; r < 4; r++) {
      pk[r][0] = pack2(p[r][0], p[r][1]);
      pk[r][1] = pack2(p[r][2], p[r][3]);
    }
    bf16x8 pf[2];
#pragma unroll
    for (int ks2 = 0; ks2 < 2; ++ks2) {
      union {
        unsigned int u[4];
        bf16x8 v;
      } cvt;
#pragma unroll
      for (int dd = 0; dd < 4; ++dd) {
        int src = lo + 16 * (((quad & 1) << 1) + (dd >> 1));
        unsigned int v0 = (unsigned int)__shfl((int)pk[2 * ks2][dd & 1], src);
        unsigned int v1 = (unsigned int)__shfl((int)pk[2 * ks2 + 1][dd & 1], src);
        cvt.u[dd] = (quad >> 1) ? v1 : v0;
      }
      pf[ks2] = cvt.v;
    }

    // O^T += V^T * P^T
#pragma unroll
    for (int dt = 0; dt < 16; ++dt) {
#pragma unroll
      for (int ks2 = 0; ks2 < 2; ++ks2) {
        int c = ks2 * 4 + quad;
        int cs = c ^ (lo & 7);
        bf16x8 vf = *(const bf16x8*)(&Vl[(dt * 16 + lo) * 64 + cs * 8]);
        oacc[dt] = MFMA16(vf, pf[ks2], oacc[dt]);
      }
    }
    __syncthreads();
  }

  // epilogue: O^T C-layout -> ctx[s_q][d]; 4 consecutive d per lane -> 8B stores
  float inv = 1.0f / l_run;
  unsigned short* cp = C + (size_t)qrow * 256;
#pragma unroll
  for (int dt = 0; dt < 16; ++dt) {
    uint2 v;
    v.x = pack2(oacc[dt][0] * inv, oacc[dt][1] * inv);
    v.y = pack2(oacc[dt][2] * inv, oacc[dt][3] * inv);
    *(uint2*)(cp + dt * 16 + quad * 4) = v;
  }
}

// ---------------- Output projection ----------------
// grid(2, 256). A = ctx (bf16), B = w_out (fp32 -> bf16), bias fp32, out fp32.
__global__ __launch_bounds__(256, 2) void proj_kernel(
    const unsigned short* __restrict__ Xc, const float* __restrict__ W,
    const float* __restrict__ bias, float* __restrict__ out) {
  __shared__ unsigned short Al[128 * 64];
  __shared__ unsigned short Bl[128 * 64];
  const int n0 = blockIdx.x * 128;
  const int m0 = blockIdx.y * 128;
  const int t = threadIdx.x;
  const int w = t >> 6, lane = t & 63, lo = lane & 15, quad = lane >> 4;
  const int aw = (w >> 1) * 64, bw = (w & 1) * 64;

  f32x4 zero4 = {0.f, 0.f, 0.f, 0.f};
  f32x4 acc[4][4];
#pragma unroll
  for (int i = 0; i < 4; i++)
#pragma unroll
    for (int j = 0; j < 4; j++) acc[i][j] = zero4;

  for (int kb = 0; kb < 4; ++kb) {
    const int k0 = kb * 64;
#pragma unroll
    for (int rr = 0; rr < 4; ++rr) {
      int ci = rr * 256 + t;
      int row = ci >> 3, c = ci & 7, cs = c ^ (row & 7);
      *(int4*)(&Al[row * 64 + cs * 8]) =
          *(const int4*)(Xc + (size_t)(m0 + row) * 256 + k0 + c * 8);
      const float* wp = W + (size_t)(n0 + row) * 256 + k0 + c * 8;
      float4 b0 = *(const float4*)wp, b1 = *(const float4*)(wp + 4);
      uint4 ub;
      ub.x = pack2(b0.x, b0.y);
      ub.y = pack2(b0.z, b0.w);
      ub.z = pack2(b1.x, b1.y);
      ub.w = pack2(b1.z, b1.w);
      *(uint4*)(&Bl[row * 64 + cs * 8]) = ub;
    }
    __syncthreads();
#pragma unroll
    for (int ks = 0; ks < 2; ++ks) {
      const int c = ks * 4 + quad, cs = c ^ (lo & 7);
      bf16x8 af[4], bfr[4];
#pragma unroll
      for (int mt = 0; mt < 4; ++mt)
        af[mt] = *(const bf16x8*)(&Al[(aw + mt * 16 + lo) * 64 + cs * 8]);
#pragma unroll
      for (int nt = 0; nt < 4; ++nt)
        bfr[nt] = *(const bf16x8*)(&Bl[(bw + nt * 16 + lo) * 64 + cs * 8]);
#pragma unroll
      for (int mt = 0; mt < 4; ++mt)
#pragma unroll
        for (int nt = 0; nt < 4; ++nt)
          acc[mt][nt] = MFMA16(af[mt], bfr[nt], acc[mt][nt]);
    }
    __syncthreads();
  }

  const int mb = m0 + aw, nb = n0 + bw;
#pragma unroll
  for (int mt = 0; mt < 4; ++mt)
#pragma unroll
    for (int nt = 0; nt < 4; ++nt) {
      int m = mb + mt * 16 + quad * 4;
      int n = nb + nt * 16 + lo;
      float bv = bias[n];
      float* p = out + (size_t)m * 256 + n;
      p[0] = acc[mt][nt][0] + bv;
      p[256] = acc[mt][nt][1] + bv;
      p[512] = acc[mt][nt][2] + bv;
      p[768] = acc[mt][nt][3] + bv;
    }
}

extern "C" void kernel_launch(void* const* d_in, const int* in_sizes, int n_in,
                              void* d_out, int out_size, void* d_ws, size_t ws_size,
                              hipStream_t stream) {
  const float* X = (const float*)d_in[0];   // x      [16,2048,256] f32
  const float* Wq = (const float*)d_in[1];  // w_qkv  [768,256]     f32
  const float* Wo = (const float*)d_in[2];  // w_out  [256,256]     f32
  const float* Bo = (const float*)d_in[3];  // b_out  [256]         f32
  float* out = (float*)d_out;
  unsigned short* ws = (unsigned short*)d_ws;

  const size_t NE = (size_t)16 * 2048 * 256;
  unsigned short* Qb = ws;           // [32768,256] bf16 (later aliased as ctx)
  unsigned short* Kb = ws + NE;      // [32768,256] bf16
  unsigned short* Vt = ws + 2 * NE;  // [16,256,2048] bf16
  unsigned short* Cx = ws;           // ctx aliases Q (safe: per-block private rows)

  qkv_kernel<<<dim3(6, 256), 256, 0, stream>>>(X, Wq, Qb, Kb, Vt);
  attn_kernel<<<dim3(32, 16), 256, 0, stream>>>(Qb, Kb, Vt, Cx);
  proj_kernel<<<dim3(2, 256), 256, 0, stream>>>(Cx, Wo, Bo, out);
}

// Round 3
// 337.768 us; speedup vs baseline: 1.1107x; 1.1107x over previous
//
#include <hip/hip_runtime.h>
#include <hip/hip_bf16.h>

// Round 3: split-KV flash attention (8 waves: 4 q-waves x 2 kv-halves, end-merge),
// padded LDS (no XOR), HW bf16 pack. qkv/proj unchanged apart from pack2 + bounds.
//   k1: qkv GEMM  x[32768,256](f32) @ w_qkv^T -> Q,K (bf16), V^T [B,D,S] bf16
//   k2: attn: S^T = K*Q^T per kv-half, online softmax, shfl P^T frags, LDS merge
//   k3: proj GEMM ctx(bf16) @ w_out^T + b_out -> out (f32)
// ws (ushort): Q/ctx[0], K[NE], Vt[2NE], NE=16*2048*256. ctx aliases Q (per-block
// private rows: Q read into regs at start, ctx written at end by same block only).

typedef short bf16x8 __attribute__((ext_vector_type(8)));
typedef float f32x4 __attribute__((ext_vector_type(4)));

#define MFMA16(a, b, c) __builtin_amdgcn_mfma_f32_16x16x32_bf16((a), (b), (c), 0, 0, 0)

__device__ __forceinline__ unsigned short f2bf(float f) {
  unsigned int x;
  __builtin_memcpy(&x, &f, 4);
  x = x + 0x7fffu + ((x >> 16) & 1u);  // RNE (finite values only)
  return (unsigned short)(x >> 16);
}
__device__ __forceinline__ unsigned int pack2(float a, float b) {
  float2 t;
  t.x = a;
  t.y = b;
  __hip_bfloat162 h = __float22bfloat162_rn(t);  // HW v_cvt_pk_bf16_f32 on gfx950
  unsigned int u;
  __builtin_memcpy(&u, &h, 4);
  return u;
}

// ---------------- QKV GEMM ----------------
// grid(6, 256), block 256. Tile 128m x 128n, BK=64. fp32 global -> bf16 LDS.
// LDS XOR-swizzled at 16B-chunk granularity (c' = c ^ (row&7)).
__global__ __launch_bounds__(256, 3) void qkv_kernel(
    const float* __restrict__ X, const float* __restrict__ W,
    unsigned short* __restrict__ Q, unsigned short* __restrict__ Kp,
    unsigned short* __restrict__ Vt) {
  __shared__ unsigned short Al[128 * 64];
  __shared__ unsigned short Bl[128 * 64];
  const int n0 = blockIdx.x * 128;
  const int m0 = blockIdx.y * 128;
  const int t = threadIdx.x;
  const int w = t >> 6, lane = t & 63, lo = lane & 15, quad = lane >> 4;
  const int aw = (w >> 1) * 64, bw = (w & 1) * 64;

  f32x4 zero4 = {0.f, 0.f, 0.f, 0.f};
  f32x4 acc[4][4];
#pragma unroll
  for (int i = 0; i < 4; i++)
#pragma unroll
    for (int j = 0; j < 4; j++) acc[i][j] = zero4;

  for (int kb = 0; kb < 4; ++kb) {
    const int k0 = kb * 64;
#pragma unroll
    for (int rr = 0; rr < 4; ++rr) {
      int ci = rr * 256 + t;
      int row = ci >> 3, c = ci & 7, cs = c ^ (row & 7);
      const float* xp = X + (size_t)(m0 + row) * 256 + k0 + c * 8;
      float4 a0 = *(const float4*)xp, a1 = *(const float4*)(xp + 4);
      uint4 ua;
      ua.x = pack2(a0.x, a0.y);
      ua.y = pack2(a0.z, a0.w);
      ua.z = pack2(a1.x, a1.y);
      ua.w = pack2(a1.z, a1.w);
      *(uint4*)(&Al[row * 64 + cs * 8]) = ua;
      const float* wp = W + (size_t)(n0 + row) * 256 + k0 + c * 8;
      float4 b0 = *(const float4*)wp, b1 = *(const float4*)(wp + 4);
      uint4 ub;
      ub.x = pack2(b0.x, b0.y);
      ub.y = pack2(b0.z, b0.w);
      ub.z = pack2(b1.x, b1.y);
      ub.w = pack2(b1.z, b1.w);
      *(uint4*)(&Bl[row * 64 + cs * 8]) = ub;
    }
    __syncthreads();
#pragma unroll
    for (int ks = 0; ks < 2; ++ks) {
      const int c = ks * 4 + quad, cs = c ^ (lo & 7);
      bf16x8 af[4], bfr[4];
#pragma unroll
      for (int mt = 0; mt < 4; ++mt)
        af[mt] = *(const bf16x8*)(&Al[(aw + mt * 16 + lo) * 64 + cs * 8]);
#pragma unroll
      for (int nt = 0; nt < 4; ++nt)
        bfr[nt] = *(const bf16x8*)(&Bl[(bw + nt * 16 + lo) * 64 + cs * 8]);
#pragma unroll
      for (int mt = 0; mt < 4; ++mt)
#pragma unroll
        for (int nt = 0; nt < 4; ++nt)
          acc[mt][nt] = MFMA16(af[mt], bfr[nt], acc[mt][nt]);
    }
    __syncthreads();
  }

  const int mb = m0 + aw, nb = n0 + bw;
  if (n0 < 256) {
#pragma unroll
    for (int mt = 0; mt < 4; ++mt)
#pragma unroll
      for (int nt = 0; nt < 4; ++nt) {
        int m = mb + mt * 16 + quad * 4;
        int n = nb + nt * 16 + lo;
        unsigned short* p = Q + (size_t)m * 256 + n;
        p[0] = f2bf(acc[mt][nt][0]);
        p[256] = f2bf(acc[mt][nt][1]);
        p[512] = f2bf(acc[mt][nt][2]);
        p[768] = f2bf(acc[mt][nt][3]);
      }
  } else if (n0 < 512) {
#pragma unroll
    for (int mt = 0; mt < 4; ++mt)
#pragma unroll
      for (int nt = 0; nt < 4; ++nt) {
        int m = mb + mt * 16 + quad * 4;
        int n = nb + nt * 16 + lo - 256;
        unsigned short* p = Kp + (size_t)m * 256 + n;
        p[0] = f2bf(acc[mt][nt][0]);
        p[256] = f2bf(acc[mt][nt][1]);
        p[512] = f2bf(acc[mt][nt][2]);
        p[768] = f2bf(acc[mt][nt][3]);
      }
  } else {
#pragma unroll
    for (int mt = 0; mt < 4; ++mt)
#pragma unroll
      for (int nt = 0; nt < 4; ++nt) {
        int m = mb + mt * 16 + quad * 4;
        int d = nb + nt * 16 + lo - 512;
        int b = m >> 11, s = m & 2047;
        uint2 v;
        v.x = pack2(acc[mt][nt][0], acc[mt][nt][1]);
        v.y = pack2(acc[mt][nt][2], acc[mt][nt][3]);
        *(uint2*)(Vt + ((size_t)(b * 256 + d)) * 2048 + s) = v;
      }
  }
}

// ---------------- Flash attention, split-KV ----------------
// grid(512), block 512 = 8 waves: wave w -> q-subtile qw=w&3 (16 rows), kv-half
// h=w>>2 (1024 kv positions, 32 iters of BN=32). End merge via LDS.
// LDS per half: K [32][264] pad-8, V^T [256][40] pad-8. 74752 B total.
__global__ __launch_bounds__(512, 4) void attn_kernel(
    const unsigned short* __restrict__ Q, const unsigned short* __restrict__ K,
    const unsigned short* __restrict__ Vt, unsigned short* __restrict__ C) {
  __shared__ __attribute__((aligned(16))) unsigned short smem[2 * 18688];
  const int id = blockIdx.x;
  const int qt = (id >> 3) & 31;                 // q-tile 0..31
  const int b = (id & 7) | ((id >> 8) << 3);     // batch: same-b blocks cluster mod 8 (XCD/L2)
  const int t = threadIdx.x;
  const int w = t >> 6, lane = t & 63, lo = lane & 15, quad = lane >> 4;
  const int h = w >> 2, qw = w & 3, tt = t & 255;
  constexpr float SCALE_LOG2E = 0.0625f * 1.4426950408889634f;

  unsigned short* Kl = smem + h * 18688;  // 32*264
  unsigned short* Vl = Kl + 8448;         // 256*40

  const int qrow = b * 2048 + qt * 64 + qw * 16 + lo;
  const unsigned short* qp = Q + (size_t)qrow * 256;
  bf16x8 qf[8];
#pragma unroll
  for (int ks = 0; ks < 8; ++ks)
    qf[ks] = *(const bf16x8*)(qp + ks * 32 + quad * 8);

  f32x4 zero4 = {0.f, 0.f, 0.f, 0.f};
  f32x4 oacc[16];
#pragma unroll
  for (int i = 0; i < 16; i++) oacc[i] = zero4;
  float m_run = -1e30f, l_run = 0.f;

  const unsigned short* Kb = K + (size_t)b * 2048 * 256;
  const unsigned short* Vb = Vt + (size_t)b * 256 * 2048;

  for (int it = 0; it < 32; ++it) {
    const int kv0 = h * 1024 + it * 32;
#pragma unroll
    for (int rr = 0; rr < 4; ++rr) {  // each half's 4 waves stage their own tiles
      int ci = rr * 256 + tt;
      int krow = ci >> 5, kc = ci & 31;
      *(int4*)(&Kl[krow * 264 + kc * 8]) =
          *(const int4*)(Kb + (size_t)(kv0 + krow) * 256 + kc * 8);
      int vd = ci >> 2, vc = ci & 3;
      *(int4*)(&Vl[vd * 40 + vc * 8]) =
          *(const int4*)(Vb + (size_t)vd * 2048 + kv0 + vc * 8);
    }
    __syncthreads();

    // S^T[s_k][s_q]: A = K rows, B = Q frags (in regs)
    f32x4 sacc[2];
    sacc[0] = zero4;
    sacc[1] = zero4;
#pragma unroll
    for (int ks = 0; ks < 8; ++ks) {
      const int c = ks * 4 + quad;
#pragma unroll
      for (int r = 0; r < 2; ++r) {
        bf16x8 kf = *(const bf16x8*)(&Kl[(r * 16 + lo) * 264 + c * 8]);
        sacc[r] = MFMA16(kf, qf[ks], sacc[r]);
      }
    }

    // online softmax: lane owns s_q = lo; 8 local s_k vals; reduce across quads
    float p[2][4];
    float cmax = -1e30f;
#pragma unroll
    for (int r = 0; r < 2; r++)
#pragma unroll
      for (int i = 0; i < 4; i++) {
        p[r][i] = sacc[r][i] * SCALE_LOG2E;
        cmax = fmaxf(cmax, p[r][i]);
      }
    cmax = fmaxf(cmax, __shfl_xor(cmax, 16));
    cmax = fmaxf(cmax, __shfl_xor(cmax, 32));
    float mnew = fmaxf(m_run, cmax);
    float rsum = 0.f;
#pragma unroll
    for (int r = 0; r < 2; r++)
#pragma unroll
      for (int i = 0; i < 4; i++) {
        p[r][i] = exp2f(p[r][i] - mnew);
        rsum += p[r][i];
      }
    rsum += __shfl_xor(rsum, 16);
    rsum += __shfl_xor(rsum, 32);
    float alpha = exp2f(m_run - mnew);
    m_run = mnew;
    l_run = l_run * alpha + rsum;
#pragma unroll
    for (int i = 0; i < 16; i++) oacc[i] *= alpha;

    // P^T B-frag via shfl: k = quad*8+dd*2+e; src lane lo+16*((quad&1)*2+(dd>>1)),
    // reg pk[quad>>1][dd&1]
    unsigned int pk[2][2];
#pragma unroll
    for (int r = 0; r < 2; r++) {
      pk[r][0] = pack2(p[r][0], p[r][1]);
      pk[r][1] = pack2(p[r][2], p[r][3]);
    }
    union {
      unsigned int u[4];
      bf16x8 v;
    } cvt;
#pragma unroll
    for (int dd = 0; dd < 4; ++dd) {
      int src = lo + 16 * (((quad & 1) << 1) | (dd >> 1));
      unsigned int v0 = (unsigned int)__shfl((int)pk[0][dd & 1], src);
      unsigned int v1 = (unsigned int)__shfl((int)pk[1][dd & 1], src);
      cvt.u[dd] = (quad >> 1) ? v1 : v0;
    }
    bf16x8 pf = cvt.v;

    // O^T += V^T * P^T
#pragma unroll
    for (int dt = 0; dt < 16; ++dt) {
      bf16x8 vf = *(const bf16x8*)(&Vl[(dt * 16 + lo) * 40 + quad * 8]);
      oacc[dt] = MFMA16(vf, pf, oacc[dt]);
    }
    __syncthreads();
  }

  // ---- merge the two kv-halves (log2 domain) ----
  float* st = (float*)smem;  // 256 floats: m[8][16], l[8][16]
  if (quad == 0) {
    st[w * 16 + lo] = m_run;
    st[128 + w * 16 + lo] = l_run;
  }
  __syncthreads();
  float m_o = st[(w ^ 4) * 16 + lo];
  float l_o = st[128 + (w ^ 4) * 16 + lo];
  float m_tot = fmaxf(m_run, m_o);
  float f_self = exp2f(m_run - m_tot);
  float l_tot = l_run * f_self + l_o * exp2f(m_o - m_tot);
  __syncthreads();
  float* Of = (float*)smem + 256;  // [qw][256 d][16 q] floats
  if (h == 1) {
#pragma unroll
    for (int dt = 0; dt < 16; ++dt)
#pragma unroll
      for (int i = 0; i < 4; ++i)
        Of[qw * 4096 + (dt * 16 + quad * 4 + i) * 16 + lo] = oacc[dt][i] * f_self;
  }
  __syncthreads();
  if (h == 0) {
    float inv = 1.0f / l_tot;
    unsigned short* cp = C + (size_t)qrow * 256;
#pragma unroll
    for (int dt = 0; dt < 16; ++dt) {
      float o0 = oacc[dt][0] * f_self + Of[qw * 4096 + (dt * 16 + quad * 4 + 0) * 16 + lo];
      float o1 = oacc[dt][1] * f_self + Of[qw * 4096 + (dt * 16 + quad * 4 + 1) * 16 + lo];
      float o2 = oacc[dt][2] * f_self + Of[qw * 4096 + (dt * 16 + quad * 4 + 2) * 16 + lo];
      float o3 = oacc[dt][3] * f_self + Of[qw * 4096 + (dt * 16 + quad * 4 + 3) * 16 + lo];
      uint2 v;
      v.x = pack2(o0 * inv, o1 * inv);
      v.y = pack2(o2 * inv, o3 * inv);
      *(uint2*)(cp + dt * 16 + quad * 4) = v;
    }
  }
}

// ---------------- Output projection ----------------
__global__ __launch_bounds__(256, 3) void proj_kernel(
    const unsigned short* __restrict__ Xc, const float* __restrict__ W,
    const float* __restrict__ bias, float* __restrict__ out) {
  __shared__ unsigned short Al[128 * 64];
  __shared__ unsigned short Bl[128 * 64];
  const int n0 = blockIdx.x * 128;
  const int m0 = blockIdx.y * 128;
  const int t = threadIdx.x;
  const int w = t >> 6, lane = t & 63, lo = lane & 15, quad = lane >> 4;
  const int aw = (w >> 1) * 64, bw = (w & 1) * 64;

  f32x4 zero4 = {0.f, 0.f, 0.f, 0.f};
  f32x4 acc[4][4];
#pragma unroll
  for (int i = 0; i < 4; i++)
#pragma unroll
    for (int j = 0; j < 4; j++) acc[i][j] = zero4;

  for (int kb = 0; kb < 4; ++kb) {
    const int k0 = kb * 64;
#pragma unroll
    for (int rr = 0; rr < 4; ++rr) {
      int ci = rr * 256 + t;
      int row = ci >> 3, c = ci & 7, cs = c ^ (row & 7);
      *(int4*)(&Al[row * 64 + cs * 8]) =
          *(const int4*)(Xc + (size_t)(m0 + row) * 256 + k0 + c * 8);
      const float* wp = W + (size_t)(n0 + row) * 256 + k0 + c * 8;
      float4 b0 = *(const float4*)wp, b1 = *(const float4*)(wp + 4);
      uint4 ub;
      ub.x = pack2(b0.x, b0.y);
      ub.y = pack2(b0.z, b0.w);
      ub.z = pack2(b1.x, b1.y);
      ub.w = pack2(b1.z, b1.w);
      *(uint4*)(&Bl[row * 64 + cs * 8]) = ub;
    }
    __syncthreads();
#pragma unroll
    for (int ks = 0; ks < 2; ++ks) {
      const int c = ks * 4 + quad, cs = c ^ (lo & 7);
      bf16x8 af[4], bfr[4];
#pragma unroll
      for (int mt = 0; mt < 4; ++mt)
        af[mt] = *(const bf16x8*)(&Al[(aw + mt * 16 + lo) * 64 + cs * 8]);
#pragma unroll
      for (int nt = 0; nt < 4; ++nt)
        bfr[nt] = *(const bf16x8*)(&Bl[(bw + nt * 16 + lo) * 64 + cs * 8]);
#pragma unroll
      for (int mt = 0; mt < 4; ++mt)
#pragma unroll
        for (int nt = 0; nt < 4; ++nt)
          acc[mt][nt] = MFMA16(af[mt], bfr[nt], acc[mt][nt]);
    }
    __syncthreads();
  }

  const int mb = m0 + aw, nb = n0 + bw;
#pragma unroll
  for (int mt = 0; mt < 4; ++mt)
#pragma unroll
    for (int nt = 0; nt < 4; ++nt) {
      int m = mb + mt * 16 + quad * 4;
      int n = nb + nt * 16 + lo;
      float bv = bias[n];
      float* p = out + (size_t)m * 256 + n;
      p[0] = acc[mt][nt][0] + bv;
      p[256] = acc[mt][nt][1] + bv;
      p[512] = acc[mt][nt][2] + bv;
      p[768] = acc[mt][nt][3] + bv;
    }
}

extern "C" void kernel_launch(void* const* d_in, const int* in_sizes, int n_in,
                              void* d_out, int out_size, void* d_ws, size_t ws_size,
                              hipStream_t stream) {
  const float* X = (const float*)d_in[0];   // x      [16,2048,256] f32
  const float* Wq = (const float*)d_in[1];  // w_qkv  [768,256]     f32
  const float* Wo = (const float*)d_in[2];  // w_out  [256,256]     f32
  const float* Bo = (const float*)d_in[3];  // b_out  [256]         f32
  float* out = (float*)d_out;
  unsigned short* ws = (unsigned short*)d_ws;

  const size_t NE = (size_t)16 * 2048 * 256;
  unsigned short* Qb = ws;           // [32768,256] bf16 (aliased as ctx later)
  unsigned short* Kb = ws + NE;      // [32768,256] bf16
  unsigned short* Vt = ws + 2 * NE;  // [16,256,2048] bf16
  unsigned short* Cx = ws;           // ctx aliases Q (per-block private rows)

  qkv_kernel<<<dim3(6, 256), 256, 0, stream>>>(X, Wq, Qb, Kb, Vt);
  attn_kernel<<<dim3(512), 512, 0, stream>>>(Qb, Kb, Vt, Cx);
  proj_kernel<<<dim3(2, 256), 256, 0, stream>>>(Cx, Wo, Bo, out);
}

// Round 4
// 257.688 us; speedup vs baseline: 1.4558x; 1.3108x over previous
//
#include <hip/hip_runtime.h>
#include <hip/hip_bf16.h>

// Round 4:
//   k1 qkv: 256 blocks; A-tile (128x256 bf16, full K) staged ONCE; loop 6 n-tiles
//           staging only B -> X read 1x from HBM (was 6x).
//   k2 attn: split-KV x2, BN=32, DOUBLE-BUFFERED async global_load_lds staging
//           (src-address XOR swizzle -> LDS writes lane-contiguous, conflict-free),
//           1 barrier/iter, merge epilogue. LDS 128KB, 1 block/CU.
//   k3 proj: unchanged.
// ws (ushort): Q/ctx[0], K[NE], Vt[2NE], NE=16*2048*256.

typedef short bf16x8 __attribute__((ext_vector_type(8)));
typedef float f32x4 __attribute__((ext_vector_type(4)));

#define MFMA16(a, b, c) __builtin_amdgcn_mfma_f32_16x16x32_bf16((a), (b), (c), 0, 0, 0)

__device__ __forceinline__ unsigned short f2bf(float f) {
  unsigned int x;
  __builtin_memcpy(&x, &f, 4);
  x = x + 0x7fffu + ((x >> 16) & 1u);
  return (unsigned short)(x >> 16);
}
__device__ __forceinline__ unsigned int pack2(float a, float b) {
  float2 t;
  t.x = a;
  t.y = b;
  __hip_bfloat162 h = __float22bfloat162_rn(t);
  unsigned int u;
  __builtin_memcpy(&u, &h, 4);
  return u;
}

// async 16B global->LDS. LDS dest is wave-uniform base + lane*16 (HW rule);
// pointers passed via integer casts (AS3 = low 32 bits of flat LDS addr).
typedef __attribute__((address_space(3))) void as3_void;
typedef __attribute__((address_space(1))) const void as1_void;
__device__ __forceinline__ void gl_lds16(const void* g, void* l) {
  __builtin_amdgcn_global_load_lds((as1_void*)(unsigned long long)g,
                                   (as3_void*)(unsigned int)(unsigned long long)l,
                                   16, 0, 0);
}

// ---------------- QKV GEMM ----------------
// grid(256), block 256 (4 waves). m-tile 128 rows; A = x tile (full K=256) in LDS
// once; loop n0 = 0..640 step 128 staging B each time. fp32->bf16 on staging.
__global__ __launch_bounds__(256, 1) void qkv_kernel(
    const float* __restrict__ X, const float* __restrict__ W,
    unsigned short* __restrict__ Q, unsigned short* __restrict__ Kp,
    unsigned short* __restrict__ Vt) {
  __shared__ unsigned short Al[128 * 256];  // 64KB, chunk-swizzle low3: s=(c&24)|((c^(row&7))&7)
  __shared__ unsigned short Bl[128 * 256];  // 64KB
  const int m0 = blockIdx.x * 128;
  const int t = threadIdx.x;
  const int w = t >> 6, lane = t & 63, lo = lane & 15, quad = lane >> 4;
  const int aw = (w >> 1) * 64, bw = (w & 1) * 64;

  // stage A once: 4096 chunks, 16 per thread
#pragma unroll
  for (int r = 0; r < 16; ++r) {
    int ci = r * 256 + t;
    int row = ci >> 5, c = ci & 31;
    int s = (c & 24) | ((c ^ (row & 7)) & 7);
    const float* xp = X + (size_t)(m0 + row) * 256 + c * 8;
    float4 a0 = *(const float4*)xp, a1 = *(const float4*)(xp + 4);
    uint4 ua;
    ua.x = pack2(a0.x, a0.y);
    ua.y = pack2(a0.z, a0.w);
    ua.z = pack2(a1.x, a1.y);
    ua.w = pack2(a1.z, a1.w);
    *(uint4*)(&Al[row * 256 + s * 8]) = ua;
  }

  for (int n = 0; n < 6; ++n) {
    const int n0 = n * 128;
    if (n > 0) __syncthreads();  // prev compute done before overwriting Bl
#pragma unroll
    for (int r = 0; r < 16; ++r) {
      int ci = r * 256 + t;
      int row = ci >> 5, c = ci & 31;
      int s = (c & 24) | ((c ^ (row & 7)) & 7);
      const float* wp = W + (size_t)(n0 + row) * 256 + c * 8;
      float4 b0 = *(const float4*)wp, b1 = *(const float4*)(wp + 4);
      uint4 ub;
      ub.x = pack2(b0.x, b0.y);
      ub.y = pack2(b0.z, b0.w);
      ub.z = pack2(b1.x, b1.y);
      ub.w = pack2(b1.z, b1.w);
      *(uint4*)(&Bl[row * 256 + s * 8]) = ub;
    }
    __syncthreads();

    f32x4 zero4 = {0.f, 0.f, 0.f, 0.f};
    f32x4 acc[4][4];
#pragma unroll
    for (int i = 0; i < 4; i++)
#pragma unroll
      for (int j = 0; j < 4; j++) acc[i][j] = zero4;

#pragma unroll
    for (int kc = 0; kc < 8; ++kc) {  // K=256 in 8 MFMA steps
      const int c = kc * 4 + quad;
      const int jj = (c & 24) | ((c ^ (lo & 7)) & 7);
      bf16x8 af[4], bfr[4];
#pragma unroll
      for (int mt = 0; mt < 4; ++mt)
        af[mt] = *(const bf16x8*)(&Al[(aw + mt * 16 + lo) * 256 + jj * 8]);
#pragma unroll
      for (int nt = 0; nt < 4; ++nt)
        bfr[nt] = *(const bf16x8*)(&Bl[(bw + nt * 16 + lo) * 256 + jj * 8]);
#pragma unroll
      for (int mt = 0; mt < 4; ++mt)
#pragma unroll
        for (int nt = 0; nt < 4; ++nt)
          acc[mt][nt] = MFMA16(af[mt], bfr[nt], acc[mt][nt]);
    }

    // epilogue for this n-tile
    const int mb = m0 + aw, nb = n0 + bw;
    if (n0 < 256) {
#pragma unroll
      for (int mt = 0; mt < 4; ++mt)
#pragma unroll
        for (int nt = 0; nt < 4; ++nt) {
          int m = mb + mt * 16 + quad * 4;
          int nn = nb + nt * 16 + lo;
          unsigned short* p = Q + (size_t)m * 256 + nn;
          p[0] = f2bf(acc[mt][nt][0]);
          p[256] = f2bf(acc[mt][nt][1]);
          p[512] = f2bf(acc[mt][nt][2]);
          p[768] = f2bf(acc[mt][nt][3]);
        }
    } else if (n0 < 512) {
#pragma unroll
      for (int mt = 0; mt < 4; ++mt)
#pragma unroll
        for (int nt = 0; nt < 4; ++nt) {
          int m = mb + mt * 16 + quad * 4;
          int nn = nb + nt * 16 + lo - 256;
          unsigned short* p = Kp + (size_t)m * 256 + nn;
          p[0] = f2bf(acc[mt][nt][0]);
          p[256] = f2bf(acc[mt][nt][1]);
          p[512] = f2bf(acc[mt][nt][2]);
          p[768] = f2bf(acc[mt][nt][3]);
        }
    } else {
#pragma unroll
      for (int mt = 0; mt < 4; ++mt)
#pragma unroll
        for (int nt = 0; nt < 4; ++nt) {
          int m = mb + mt * 16 + quad * 4;
          int d = nb + nt * 16 + lo - 512;
          int b = m >> 11, s = m & 2047;
          uint2 v;
          v.x = pack2(acc[mt][nt][0], acc[mt][nt][1]);
          v.y = pack2(acc[mt][nt][2], acc[mt][nt][3]);
          *(uint2*)(Vt + ((size_t)(b * 256 + d)) * 2048 + s) = v;
        }
    }
  }
}

// ---------------- Flash attention, split-KV, async double-buffer ----------------
// grid(512), block 512 = 8 waves: wave w -> q-subtile qw=w&3, kv-half h=w>>2.
// BN=32, 32 iters. LDS: buf p in {0,1}: [p][h][ K 32x256 | V^T 256x32 ] = 128KB.
// K stored with src-XOR swizzle: chunk (krow,j) holds global col-chunk
// (j&16)|((j^(krow&15))&15). V chunk (vd,j) holds global s-chunk j^(vd&3).
__global__ __launch_bounds__(512, 2) void attn_kernel(
    const unsigned short* __restrict__ Q, const unsigned short* __restrict__ K,
    const unsigned short* __restrict__ Vt, unsigned short* __restrict__ C) {
  __shared__ __attribute__((aligned(16))) unsigned short smem[65536];  // 131072 B
  const int id = blockIdx.x;
  const int qt = (id >> 3) & 31;
  const int b = (id & 7) | ((id >> 8) << 3);
  const int t = threadIdx.x;
  const int w = t >> 6, lane = t & 63, lo = lane & 15, quad = lane >> 4;
  const int h = w >> 2, qw = w & 3;
  constexpr float SCALE_LOG2E = 0.0625f * 1.4426950408889634f;

  const unsigned short* Kb = K + (size_t)b * 2048 * 256;
  const unsigned short* Vb = Vt + (size_t)b * 256 * 2048;

  // --- staging setup: 8 chunks/thread (4 K + 4 V) ---
  const unsigned short* gk[4];
  const unsigned short* gv[4];
  int loK[4], loV[4];  // wave-uniform LDS base offsets (ushort units) within buffer
#pragma unroll
  for (int r = 0; r < 4; ++r) {
    int kidx = r * 512 + t;                 // 0..2047 over K chunks (both halves)
    int kh = kidx >> 10, c2 = kidx & 1023;  // half, chunk within half
    int krow = c2 >> 5, j = c2 & 31;
    int srcc = (j & 16) | ((j ^ (krow & 15)) & 15);
    gk[r] = Kb + (size_t)(kh * 1024 + krow) * 256 + srcc * 8;
    int cb = (r * 512 + w * 64) & 1023;  // wave-uniform chunk base within half
    loK[r] = kh * 16384 + cb * 8;

    int vidx = r * 512 + t;
    int vh = vidx >> 10, v2 = vidx & 1023;
    int vd = v2 >> 2, vj = v2 & 3;
    int srcj = vj ^ (vd & 3);
    gv[r] = Vb + (size_t)vd * 2048 + vh * 1024 + srcj * 8;
    int vb2 = (r * 512 + w * 64) & 1023;
    loV[r] = vh * 16384 + 8192 + vb2 * 8;
  }

  // --- Q fragments (B-operand) ---
  const int qrow = b * 2048 + qt * 64 + qw * 16 + lo;
  const unsigned short* qp = Q + (size_t)qrow * 256;
  bf16x8 qf[8];
#pragma unroll
  for (int ks = 0; ks < 8; ++ks)
    qf[ks] = *(const bf16x8*)(qp + ks * 32 + quad * 8);

  f32x4 zero4 = {0.f, 0.f, 0.f, 0.f};
  f32x4 oacc[16];
#pragma unroll
  for (int i = 0; i < 16; i++) oacc[i] = zero4;
  float m_run = -1e30f, l_run = 0.f;

  // prologue: prefetch iter 0 into buffer 0
#pragma unroll
  for (int r = 0; r < 4; ++r) gl_lds16(gk[r], &smem[loK[r]]);
#pragma unroll
  for (int r = 0; r < 4; ++r) gl_lds16(gv[r], &smem[loV[r]]);
#pragma unroll
  for (int r = 0; r < 4; ++r) {
    gk[r] += 32 * 256;
    gv[r] += 32;
  }

  for (int it = 0; it < 32; ++it) {
    asm volatile("s_waitcnt vmcnt(0)" ::: "memory");
    __syncthreads();
    if (it < 31) {
      const int pn = (it + 1) & 1;
#pragma unroll
      for (int r = 0; r < 4; ++r) gl_lds16(gk[r], &smem[pn * 32768 + loK[r]]);
#pragma unroll
      for (int r = 0; r < 4; ++r) gl_lds16(gv[r], &smem[pn * 32768 + loV[r]]);
#pragma unroll
      for (int r = 0; r < 4; ++r) {
        gk[r] += 32 * 256;
        gv[r] += 32;
      }
    }
    const unsigned short* Kl = smem + (it & 1) * 32768 + h * 16384;
    const unsigned short* Vl = Kl + 8192;

    // S^T[s_k][s_q]: A = K rows, B = Q frags
    f32x4 sacc[2];
    sacc[0] = zero4;
    sacc[1] = zero4;
#pragma unroll
    for (int ks = 0; ks < 8; ++ks) {
      const int c = ks * 4 + quad;
      const int jj = (c & 16) | ((c ^ lo) & 15);
#pragma unroll
      for (int r = 0; r < 2; ++r) {
        bf16x8 kf = *(const bf16x8*)(&Kl[(r * 16 + lo) * 256 + jj * 8]);
        sacc[r] = MFMA16(kf, qf[ks], sacc[r]);
      }
    }

    // online softmax (lane owns s_q = lo; reduce across quads)
    float p[2][4];
    float cmax = -1e30f;
#pragma unroll
    for (int r = 0; r < 2; r++)
#pragma unroll
      for (int i = 0; i < 4; i++) {
        p[r][i] = sacc[r][i] * SCALE_LOG2E;
        cmax = fmaxf(cmax, p[r][i]);
      }
    cmax = fmaxf(cmax, __shfl_xor(cmax, 16));
    cmax = fmaxf(cmax, __shfl_xor(cmax, 32));
    float mnew = fmaxf(m_run, cmax);
    float rsum = 0.f;
#pragma unroll
    for (int r = 0; r < 2; r++)
#pragma unroll
      for (int i = 0; i < 4; i++) {
        p[r][i] = exp2f(p[r][i] - mnew);
        rsum += p[r][i];
      }
    rsum += __shfl_xor(rsum, 16);
    rsum += __shfl_xor(rsum, 32);
    float alpha = exp2f(m_run - mnew);
    m_run = mnew;
    l_run = l_run * alpha + rsum;
#pragma unroll
    for (int i = 0; i < 16; i++) oacc[i] *= alpha;

    // P^T B-frag via shfl
    unsigned int pk[2][2];
#pragma unroll
    for (int r = 0; r < 2; r++) {
      pk[r][0] = pack2(p[r][0], p[r][1]);
      pk[r][1] = pack2(p[r][2], p[r][3]);
    }
    union {
      unsigned int u[4];
      bf16x8 v;
    } cvt;
#pragma unroll
    for (int dd = 0; dd < 4; ++dd) {
      int src = lo + 16 * (((quad & 1) << 1) | (dd >> 1));
      unsigned int v0 = (unsigned int)__shfl((int)pk[0][dd & 1], src);
      unsigned int v1 = (unsigned int)__shfl((int)pk[1][dd & 1], src);
      cvt.u[dd] = (quad >> 1) ? v1 : v0;
    }
    bf16x8 pf = cvt.v;

    // O^T += V^T * P^T
#pragma unroll
    for (int dt = 0; dt < 16; ++dt) {
      bf16x8 vf = *(const bf16x8*)(&Vl[(dt * 16 + lo) * 32 + ((quad ^ (lo & 3)) * 8)]);
      oacc[dt] = MFMA16(vf, pf, oacc[dt]);
    }
  }

  // ---- merge the two kv-halves (log2 domain); smem reused as scratch ----
  float* st = (float*)smem;  // 256 floats (lives in buf0; iter-31 computed on buf1)
  if (quad == 0) {
    st[w * 16 + lo] = m_run;
    st[128 + w * 16 + lo] = l_run;
  }
  __syncthreads();
  float m_o = st[(w ^ 4) * 16 + lo];
  float l_o = st[128 + (w ^ 4) * 16 + lo];
  float m_tot = fmaxf(m_run, m_o);
  float f_self = exp2f(m_run - m_tot);
  float l_tot = l_run * f_self + l_o * exp2f(m_o - m_tot);
  __syncthreads();
  float* Of = (float*)smem + 256;  // [qw][256 d][16 q] floats = 64KB
  if (h == 1) {
#pragma unroll
    for (int dt = 0; dt < 16; ++dt)
#pragma unroll
      for (int i = 0; i < 4; ++i)
        Of[qw * 4096 + (dt * 16 + quad * 4 + i) * 16 + lo] = oacc[dt][i] * f_self;
  }
  __syncthreads();
  if (h == 0) {
    float inv = 1.0f / l_tot;
    unsigned short* cp = C + (size_t)qrow * 256;
#pragma unroll
    for (int dt = 0; dt < 16; ++dt) {
      float o0 = oacc[dt][0] * f_self + Of[qw * 4096 + (dt * 16 + quad * 4 + 0) * 16 + lo];
      float o1 = oacc[dt][1] * f_self + Of[qw * 4096 + (dt * 16 + quad * 4 + 1) * 16 + lo];
      float o2 = oacc[dt][2] * f_self + Of[qw * 4096 + (dt * 16 + quad * 4 + 2) * 16 + lo];
      float o3 = oacc[dt][3] * f_self + Of[qw * 4096 + (dt * 16 + quad * 4 + 3) * 16 + lo];
      uint2 v;
      v.x = pack2(o0 * inv, o1 * inv);
      v.y = pack2(o2 * inv, o3 * inv);
      *(uint2*)(cp + dt * 16 + quad * 4) = v;
    }
  }
}

// ---------------- Output projection ----------------
__global__ __launch_bounds__(256, 3) void proj_kernel(
    const unsigned short* __restrict__ Xc, const float* __restrict__ W,
    const float* __restrict__ bias, float* __restrict__ out) {
  __shared__ unsigned short Al[128 * 64];
  __shared__ unsigned short Bl[128 * 64];
  const int n0 = blockIdx.x * 128;
  const int m0 = blockIdx.y * 128;
  const int t = threadIdx.x;
  const int w = t >> 6, lane = t & 63, lo = lane & 15, quad = lane >> 4;
  const int aw = (w >> 1) * 64, bw = (w & 1) * 64;

  f32x4 zero4 = {0.f, 0.f, 0.f, 0.f};
  f32x4 acc[4][4];
#pragma unroll
  for (int i = 0; i < 4; i++)
#pragma unroll
    for (int j = 0; j < 4; j++) acc[i][j] = zero4;

  for (int kb = 0; kb < 4; ++kb) {
    const int k0 = kb * 64;
#pragma unroll
    for (int rr = 0; rr < 4; ++rr) {
      int ci = rr * 256 + t;
      int row = ci >> 3, c = ci & 7, cs = c ^ (row & 7);
      *(int4*)(&Al[row * 64 + cs * 8]) =
          *(const int4*)(Xc + (size_t)(m0 + row) * 256 + k0 + c * 8);
      const float* wp = W + (size_t)(n0 + row) * 256 + k0 + c * 8;
      float4 b0 = *(const float4*)wp, b1 = *(const float4*)(wp + 4);
      uint4 ub;
      ub.x = pack2(b0.x, b0.y);
      ub.y = pack2(b0.z, b0.w);
      ub.z = pack2(b1.x, b1.y);
      ub.w = pack2(b1.z, b1.w);
      *(uint4*)(&Bl[row * 64 + cs * 8]) = ub;
    }
    __syncthreads();
#pragma unroll
    for (int ks = 0; ks < 2; ++ks) {
      const int c = ks * 4 + quad, cs = c ^ (lo & 7);
      bf16x8 af[4], bfr[4];
#pragma unroll
      for (int mt = 0; mt < 4; ++mt)
        af[mt] = *(const bf16x8*)(&Al[(aw + mt * 16 + lo) * 64 + cs * 8]);
#pragma unroll
      for (int nt = 0; nt < 4; ++nt)
        bfr[nt] = *(const bf16x8*)(&Bl[(bw + nt * 16 + lo) * 64 + cs * 8]);
#pragma unroll
      for (int mt = 0; mt < 4; ++mt)
#pragma unroll
        for (int nt = 0; nt < 4; ++nt)
          acc[mt][nt] = MFMA16(af[mt], bfr[nt], acc[mt][nt]);
    }
    __syncthreads();
  }

  const int mb = m0 + aw, nb = n0 + bw;
#pragma unroll
  for (int mt = 0; mt < 4; ++mt)
#pragma unroll
    for (int nt = 0; nt < 4; ++nt) {
      int m = mb + mt * 16 + quad * 4;
      int n = nb + nt * 16 + lo;
      float bv = bias[n];
      float* p = out + (size_t)m * 256 + n;
      p[0] = acc[mt][nt][0] + bv;
      p[256] = acc[mt][nt][1] + bv;
      p[512] = acc[mt][nt][2] + bv;
      p[768] = acc[mt][nt][3] + bv;
    }
}

extern "C" void kernel_launch(void* const* d_in, const int* in_sizes, int n_in,
                              void* d_out, int out_size, void* d_ws, size_t ws_size,
                              hipStream_t stream) {
  const float* X = (const float*)d_in[0];
  const float* Wq = (const float*)d_in[1];
  const float* Wo = (const float*)d_in[2];
  const float* Bo = (const float*)d_in[3];
  float* out = (float*)d_out;
  unsigned short* ws = (unsigned short*)d_ws;

  const size_t NE = (size_t)16 * 2048 * 256;
  unsigned short* Qb = ws;
  unsigned short* Kb = ws + NE;
  unsigned short* Vt = ws + 2 * NE;
  unsigned short* Cx = ws;  // ctx aliases Q (per-block private rows)

  qkv_kernel<<<dim3(256), 256, 0, stream>>>(X, Wq, Qb, Kb, Vt);
  attn_kernel<<<dim3(512), 512, 0, stream>>>(Qb, Kb, Vt, Cx);
  proj_kernel<<<dim3(2, 256), 256, 0, stream>>>(Cx, Wo, Bo, out);
}